// Round 5
// baseline (1534.557 us; speedup 1.0000x reference)
//
#include <hip/hip_runtime.h>
#include <math.h>

// GCN: h0 = lrelu(Agg(x@W0)+b0); h1 = lrelu(Agg(h0@W1)+b1); out = sigmoid(h1[idx]@Wm+bm)
// Agg (sym-norm + self loops): agg[d] = dinv[d] * ( sum_{e:dst=d} hs[src] + hs[d] ),
// hs = h * dinv[row] (pre-scaled in GEMM epilogue).
// Edges are partition-binned by dst-bucket (64 nodes/bucket): 64 partition blocks
// build LDS histograms, bucket-major scan gives each (bucket,partition) an exclusive
// region -> scatter writes are XCD-local and L2-combined (no cross-XCD line bounce).
// Aggregation: block per bucket, LDS float accumulator + ds_add_f32, coalesced store.
// GEMM: lane=row, direct per-lane float4 row loads (no LDS, no barriers), W via
// wave-uniform s_load, acc[16] per lane (wave = 16-col slice).

#define NPART 64
#define MAXB 2048  // max dst-buckets supported (N <= 131072)

__device__ __forceinline__ float lrelu(float x) { return x > 0.0f ? x : 0.01f * x; }

// ---------- degree ----------

__global__ void k_hist(const int* __restrict__ dst, int E, int* __restrict__ cnt) {
    int i = blockIdx.x * blockDim.x + threadIdx.x;
    if (i < E) atomicAdd(cnt + dst[i], 1);
}

__global__ void k_dinv(const int* __restrict__ cnt, float* __restrict__ dinv, int N) {
    int i = blockIdx.x * blockDim.x + threadIdx.x;
    if (i < N) dinv[i] = rsqrtf((float)cnt[i] + 1.0f);  // +1 self loop
}

// ---------- partitioned binning ----------

__global__ __launch_bounds__(256) void k_part_hist(const int* __restrict__ dst, int E,
                                                   int B, int* __restrict__ phist) {
    __shared__ int scnt[MAXB];
    int t = threadIdx.x, p = blockIdx.x;
    for (int i = t; i < B; i += 256) scnt[i] = 0;
    __syncthreads();
    int ep = (E + NPART - 1) / NPART;
    int beg = p * ep, endi = min(E, beg + ep);
    for (int e = beg + t; e < endi; e += 256)
        atomicAdd(&scnt[dst[e] >> 6], 1);
    __syncthreads();
    for (int i = t; i < B; i += 256) phist[i * NPART + p] = scnt[i];
}

__global__ __launch_bounds__(256) void k_part_scatter(const int* __restrict__ src,
                                                      const int* __restrict__ dst, int E,
                                                      int B, const int* __restrict__ pbase,
                                                      int* __restrict__ esorted) {
    __shared__ int sbase[MAXB];
    int t = threadIdx.x, p = blockIdx.x;
    for (int i = t; i < B; i += 256) sbase[i] = pbase[i * NPART + p];
    __syncthreads();
    int ep = (E + NPART - 1) / NPART;
    int beg = p * ep, endi = min(E, beg + ep);
    for (int e = beg + t; e < endi; e += 256) {
        int d = dst[e];
        int pos = atomicAdd(&sbase[d >> 6], 1);
        esorted[pos] = ((d & 63) << 24) | src[e];  // src < 2^24
    }
}

// ---------- scan (generic, 1024 elems per chunk-block) ----------

__global__ void k_blocksum(const int* __restrict__ cnt, int N, int* __restrict__ bsum) {
    __shared__ int sm[256];
    int b = blockIdx.x, t = threadIdx.x;
    int base = b * 1024 + t * 4;
    int s = 0;
#pragma unroll
    for (int i = 0; i < 4; ++i) { int j = base + i; if (j < N) s += cnt[j]; }
    sm[t] = s; __syncthreads();
    for (int off = 128; off > 0; off >>= 1) {
        if (t < off) sm[t] += sm[t + off];
        __syncthreads();
    }
    if (t == 0) bsum[b] = sm[0];
}

__global__ void k_scan_bsum(int* __restrict__ bsum, int nb, int* __restrict__ offN) {
    __shared__ int sm[1024];
    int t = threadIdx.x;
    int v = (t < nb) ? bsum[t] : 0;
    sm[t] = v; __syncthreads();
    for (int d = 1; d < 1024; d <<= 1) {
        int add = (t >= d) ? sm[t - d] : 0;
        __syncthreads();
        sm[t] += add;
        __syncthreads();
    }
    if (t < nb) bsum[t] = sm[t] - v;       // exclusive
    if (t == nb - 1) *offN = sm[t];        // total == E
}

__global__ void k_scan_block(const int* __restrict__ cnt, const int* __restrict__ bsum,
                             int* __restrict__ off, int N) {
    __shared__ int sm[256];
    int b = blockIdx.x, t = threadIdx.x;
    int base = b * 1024 + t * 4;
    int v[4];
#pragma unroll
    for (int i = 0; i < 4; ++i) { int j = base + i; v[i] = (j < N) ? cnt[j] : 0; }
    int tsum = v[0] + v[1] + v[2] + v[3];
    sm[t] = tsum; __syncthreads();
    for (int d = 1; d < 256; d <<= 1) {
        int val = (t >= d) ? sm[t - d] : 0;
        __syncthreads();
        sm[t] += val;
        __syncthreads();
    }
    int run = sm[t] - tsum + bsum[b];
#pragma unroll
    for (int i = 0; i < 4; ++i) {
        int j = base + i;
        if (j < N) off[j] = run;
        run += v[i];
    }
}

// ---------- GEMM: lane=row, direct loads, no barriers ----------

template <int K, bool TRANS>  // TRANS: x := lrelu(x + b0[k]) on load
__global__ __launch_bounds__(256) void k_gemm(const float* __restrict__ A,
                                              const float* __restrict__ W,
                                              const float* __restrict__ b0,
                                              const float* __restrict__ dinv,
                                              float* __restrict__ hout, int N) {
    int lane = threadIdx.x & 63;
    int wvu = __builtin_amdgcn_readfirstlane(threadIdx.x >> 6);
    int row = blockIdx.x * 64 + lane;
    int rr = row < N ? row : N - 1;
    const float* a = A + (size_t)rr * K;
    float acc[16];
#pragma unroll
    for (int i = 0; i < 16; ++i) acc[i] = 0.0f;

#pragma unroll
    for (int k4 = 0; k4 < K / 4; ++k4) {
        float4 xq = *(const float4*)(a + k4 * 4);
        if (TRANS) {
            float4 bq = *(const float4*)(b0 + k4 * 4);  // wave-uniform -> s_load
            xq.x = lrelu(xq.x + bq.x); xq.y = lrelu(xq.y + bq.y);
            xq.z = lrelu(xq.z + bq.z); xq.w = lrelu(xq.w + bq.w);
        }
#pragma unroll
        for (int j = 0; j < 4; ++j) {
            float xv = (j == 0) ? xq.x : (j == 1) ? xq.y : (j == 2) ? xq.z : xq.w;
            const float4* W4 = (const float4*)(W + (size_t)(k4 * 4 + j) * 64 + wvu * 16);
            float4 w0 = W4[0], w1 = W4[1], w2 = W4[2], w3 = W4[3];  // scalar loads
            acc[0]  = fmaf(xv, w0.x, acc[0]);  acc[1]  = fmaf(xv, w0.y, acc[1]);
            acc[2]  = fmaf(xv, w0.z, acc[2]);  acc[3]  = fmaf(xv, w0.w, acc[3]);
            acc[4]  = fmaf(xv, w1.x, acc[4]);  acc[5]  = fmaf(xv, w1.y, acc[5]);
            acc[6]  = fmaf(xv, w1.z, acc[6]);  acc[7]  = fmaf(xv, w1.w, acc[7]);
            acc[8]  = fmaf(xv, w2.x, acc[8]);  acc[9]  = fmaf(xv, w2.y, acc[9]);
            acc[10] = fmaf(xv, w2.z, acc[10]); acc[11] = fmaf(xv, w2.w, acc[11]);
            acc[12] = fmaf(xv, w3.x, acc[12]); acc[13] = fmaf(xv, w3.y, acc[13]);
            acc[14] = fmaf(xv, w3.z, acc[14]); acc[15] = fmaf(xv, w3.w, acc[15]);
        }
    }

    if (row >= N) return;
    float dv = dinv[row];
    float* o = hout + (size_t)row * 64 + wvu * 16;
#pragma unroll
    for (int q = 0; q < 4; ++q) {
        float4 v;
        v.x = acc[4 * q + 0] * dv; v.y = acc[4 * q + 1] * dv;
        v.z = acc[4 * q + 2] * dv; v.w = acc[4 * q + 3] * dv;
        *(float4*)(o + 4 * q) = v;
    }
}

// ---------- aggregation: block per 64-node bucket, LDS accumulator ----------

__global__ __launch_bounds__(256) void k_agg(const int* __restrict__ pbase, int BP,
                                             const int* __restrict__ esorted,
                                             const float* __restrict__ dinv,
                                             const float* __restrict__ hs,
                                             float* __restrict__ agg, int N) {
    __shared__ float acc[64 * 64];
    int t = threadIdx.x;
    int lane = t & 63;
    int wvu = __builtin_amdgcn_readfirstlane(t >> 6);
    int b = blockIdx.x;
    int base = b * 64;

    {   // init with self-loop term (hs row)
        int r = t >> 2, q = t & 3;
        int g = base + r;
        if (g < N) {
            const float4* sp = (const float4*)(hs + (size_t)g * 64 + q * 16);
            float4* dp = (float4*)(acc + r * 64 + q * 16);
#pragma unroll
            for (int j = 0; j < 4; ++j) dp[j] = sp[j];
        }
    }
    __syncthreads();

    int beg  = pbase[b * NPART];
    int endi = pbase[min((b + 1) * NPART, BP)];
    for (int e = beg + wvu * 2; e < endi; e += 8) {
        int v0 = esorted[e];
        bool two = (e + 1 < endi);
        int v1 = two ? esorted[e + 1] : 0;
        float x0 = hs[(size_t)(v0 & 0xFFFFFF) * 64 + lane];
        float x1 = two ? hs[(size_t)(v1 & 0xFFFFFF) * 64 + lane] : 0.0f;
        atomicAdd(&acc[((v0 >> 24) & 63) * 64 + lane], x0);
        if (two) atomicAdd(&acc[((v1 >> 24) & 63) * 64 + lane], x1);
    }
    __syncthreads();

    {   // scaled writeback (coalesced)
        int r = t >> 2, q = t & 3;
        int g = base + r;
        if (g < N) {
            float dv = dinv[g];
            float4* op = (float4*)(agg + (size_t)g * 64 + q * 16);
            const float4* ap = (const float4*)(acc + r * 64 + q * 16);
#pragma unroll
            for (int j = 0; j < 4; ++j) {
                float4 v = ap[j];
                v.x *= dv; v.y *= dv; v.z *= dv; v.w *= dv;
                op[j] = v;
            }
        }
    }
}

// ---------- epilogue ----------

__global__ void k_out(const int* __restrict__ idx, const float* __restrict__ agg,
                      const float* __restrict__ b1, const float* __restrict__ Wm,
                      const float* __restrict__ bm, float* __restrict__ out, int NSEL) {
    int lane = threadIdx.x & 63;
    int wv = (blockIdx.x * blockDim.x + threadIdx.x) >> 6;
    if (wv >= NSEL) return;
    int node = idx[wv];
    float hs = lrelu(agg[(size_t)node * 64 + lane] + b1[lane]);
    out[(size_t)wv * 64 + lane] = hs;
#pragma unroll
    for (int o = 0; o < 5; ++o) {
        float p = hs * Wm[lane * 5 + o];
#pragma unroll
        for (int offs = 32; offs > 0; offs >>= 1) p += __shfl_down(p, offs);
        if (lane == 0)
            out[(size_t)NSEL * 64 + (size_t)wv * 5 + o] =
                1.0f / (1.0f + expf(-(p + bm[o])));
    }
}

extern "C" void kernel_launch(void* const* d_in, const int* in_sizes, int n_in,
                              void* d_out, int out_size, void* d_ws, size_t ws_size,
                              hipStream_t stream) {
    const float* x   = (const float*)d_in[0];
    const int*   ei  = (const int*)d_in[1];
    const int*   idx = (const int*)d_in[2];
    const float* W0  = (const float*)d_in[3];
    const float* b0  = (const float*)d_in[4];
    const float* W1  = (const float*)d_in[5];
    const float* b1  = (const float*)d_in[6];
    const float* Wm  = (const float*)d_in[7];
    const float* bm  = (const float*)d_in[8];

    int N    = in_sizes[0] / 128;
    int E    = in_sizes[1] / 2;
    int NSEL = in_sizes[2];
    const int* src = ei;
    const int* dst = ei + E;

    int B  = (N + 63) / 64;      // dst buckets (64 nodes each)
    int BP = B * NPART;          // scan length

    char* w = (char*)d_ws;
    size_t Na  = ((size_t)N + 1023) & ~(size_t)1023;
    size_t Ea  = ((size_t)E + 1023) & ~(size_t)1023;
    size_t BPa = ((size_t)BP + 1023) & ~(size_t)1023;
    float* dinv    = (float*)w;                 w += Na * 4;
    int*   cnt     = (int*)w;                   w += Na * 4;
    int*   phist   = (int*)w;                   w += BPa * 4;
    int*   pbase   = (int*)w;                   w += (BPa + 1024) * 4;
    int*   bsum    = (int*)w;                   w += 1024 * 4;
    int*   esorted = (int*)w;                   w += Ea * 4;
    float* buf1    = (float*)w;                 w += (size_t)N * 64 * 4;  // hs
    float* buf2    = (float*)w;                                          // agg

    int nbp = (BP + 1023) / 1024;

    hipMemsetAsync(cnt, 0, (size_t)N * sizeof(int), stream);
    k_hist<<<(E + 255) / 256, 256, 0, stream>>>(dst, E, cnt);
    k_dinv<<<(N + 255) / 256, 256, 0, stream>>>(cnt, dinv, N);

    k_part_hist<<<NPART, 256, 0, stream>>>(dst, E, B, phist);
    k_blocksum<<<nbp, 256, 0, stream>>>(phist, BP, bsum);
    k_scan_bsum<<<1, 1024, 0, stream>>>(bsum, nbp, pbase + BP);
    k_scan_block<<<nbp, 256, 0, stream>>>(phist, bsum, pbase, BP);
    k_part_scatter<<<NPART, 256, 0, stream>>>(src, dst, E, B, pbase, esorted);

    int gemm_blocks = (N + 63) / 64;

    k_gemm<128, false><<<gemm_blocks, 256, 0, stream>>>(x, W0, nullptr, dinv, buf1, N);
    k_agg<<<B, 256, 0, stream>>>(pbase, BP, esorted, dinv, buf1, buf2, N);
    k_gemm<64, true><<<gemm_blocks, 256, 0, stream>>>(buf2, W1, b0, dinv, buf1, N);
    k_agg<<<B, 256, 0, stream>>>(pbase, BP, esorted, dinv, buf1, buf2, N);
    k_out<<<(NSEL + 3) / 4, 256, 0, stream>>>(idx, buf2, b1, Wm, bm, (float*)d_out, NSEL);
}

// Round 6
// 444.488 us; speedup vs baseline: 3.4524x; 3.4524x over previous
//
#include <hip/hip_runtime.h>
#include <hip/hip_fp16.h>
#include <math.h>

// GCN: h0 = lrelu(Agg(x@W0)+b0); h1 = lrelu(Agg(h0@W1)+b1); out = sigmoid(h1[idx]@Wm+bm)
// Agg (sym-norm + self loops): agg[d] = dinv[d] * ( sum_{e:dst=d} hs[src] + hs[d] ),
// hs = h * dinv[row], stored FP16 (gather payload) -> halves LLC gather bytes.
// CSR build: partition-binned scatter into 64-node buckets (XCD-local, write-combined),
// then per-bucket LDS counting sort -> node-ordered edge list + off[] + dinv[]
// (no global-atomic histogram, no N-scan). Agg: one wave per node, 4 gathers in flight.

#define NPART 64
#define MAXB 2048  // max dst-buckets (N <= 131072)

__device__ __forceinline__ float lrelu(float x) { return x > 0.0f ? x : 0.01f * x; }

// ---------- partitioned binning ----------

__global__ __launch_bounds__(256) void k_part_hist(const int* __restrict__ dst, int E,
                                                   int B, int* __restrict__ phist) {
    __shared__ int scnt[MAXB];
    int t = threadIdx.x, p = blockIdx.x;
    for (int i = t; i < B; i += 256) scnt[i] = 0;
    __syncthreads();
    int ep = (E + NPART - 1) / NPART;
    int beg = p * ep, endi = min(E, beg + ep);
    for (int e = beg + t; e < endi; e += 256)
        atomicAdd(&scnt[dst[e] >> 6], 1);
    __syncthreads();
    for (int i = t; i < B; i += 256) phist[i * NPART + p] = scnt[i];
}

__global__ __launch_bounds__(256) void k_part_scatter(const int* __restrict__ src,
                                                      const int* __restrict__ dst, int E,
                                                      int B, const int* __restrict__ pbase,
                                                      int* __restrict__ esA) {
    __shared__ int sbase[MAXB];
    int t = threadIdx.x, p = blockIdx.x;
    for (int i = t; i < B; i += 256) sbase[i] = pbase[i * NPART + p];
    __syncthreads();
    int ep = (E + NPART - 1) / NPART;
    int beg = p * ep, endi = min(E, beg + ep);
    for (int e = beg + t; e < endi; e += 256) {
        int d = dst[e];
        int pos = atomicAdd(&sbase[d >> 6], 1);
        esA[pos] = ((d & 63) << 24) | src[e];  // src < 2^24
    }
}

// ---------- scan over BP = B*NPART ----------

__global__ void k_blocksum(const int* __restrict__ cnt, int N, int* __restrict__ bsum) {
    __shared__ int sm[256];
    int b = blockIdx.x, t = threadIdx.x;
    int base = b * 1024 + t * 4;
    int s = 0;
#pragma unroll
    for (int i = 0; i < 4; ++i) { int j = base + i; if (j < N) s += cnt[j]; }
    sm[t] = s; __syncthreads();
    for (int off = 128; off > 0; off >>= 1) {
        if (t < off) sm[t] += sm[t + off];
        __syncthreads();
    }
    if (t == 0) bsum[b] = sm[0];
}

__global__ void k_scan_bsum(int* __restrict__ bsum, int nb, int* __restrict__ offN) {
    __shared__ int sm[1024];
    int t = threadIdx.x;
    int v = (t < nb) ? bsum[t] : 0;
    sm[t] = v; __syncthreads();
    for (int d = 1; d < 1024; d <<= 1) {
        int add = (t >= d) ? sm[t - d] : 0;
        __syncthreads();
        sm[t] += add;
        __syncthreads();
    }
    if (t < nb) bsum[t] = sm[t] - v;       // exclusive
    if (t == nb - 1) *offN = sm[t];        // total == E
}

__global__ void k_scan_block(const int* __restrict__ cnt, const int* __restrict__ bsum,
                             int* __restrict__ off, int N) {
    __shared__ int sm[256];
    int b = blockIdx.x, t = threadIdx.x;
    int base = b * 1024 + t * 4;
    int v[4];
#pragma unroll
    for (int i = 0; i < 4; ++i) { int j = base + i; v[i] = (j < N) ? cnt[j] : 0; }
    int tsum = v[0] + v[1] + v[2] + v[3];
    sm[t] = tsum; __syncthreads();
    for (int d = 1; d < 256; d <<= 1) {
        int val = (t >= d) ? sm[t - d] : 0;
        __syncthreads();
        sm[t] += val;
        __syncthreads();
    }
    int run = sm[t] - tsum + bsum[b];
#pragma unroll
    for (int i = 0; i < 4; ++i) {
        int j = base + i;
        if (j < N) off[j] = run;
        run += v[i];
    }
}

// ---------- per-bucket counting sort -> node-ordered edges + off[] + dinv[] ----------

__global__ __launch_bounds__(256) void k_bsort(const int* __restrict__ pbase, int BP,
                                               const int* __restrict__ esA,
                                               int* __restrict__ esB,
                                               int* __restrict__ off,
                                               float* __restrict__ dinv,
                                               int N, int E) {
    __shared__ int hcnt[64];
    __shared__ int hoff[64];
    int t = threadIdx.x, b = blockIdx.x;
    int start = pbase[b * NPART];
    int endi  = pbase[min((b + 1) * NPART, BP)];
    if (b == (int)gridDim.x - 1) endi = E;

    if (t < 64) hcnt[t] = 0;
    __syncthreads();
    for (int e = start + t; e < endi; e += 256)
        atomicAdd(&hcnt[(esA[e] >> 24) & 63], 1);
    __syncthreads();

    if (t < 64) {  // wave 0: 64-wide inclusive scan -> exclusive offsets
        int c = hcnt[t];
        int v = c;
#pragma unroll
        for (int d = 1; d < 64; d <<= 1) {
            int u = __shfl_up(v, d);
            if (t >= d) v += u;
        }
        int pos = start + (v - c);
        hoff[t] = pos;
        int g = b * 64 + t;
        if (g < N) {
            off[g] = pos;
            dinv[g] = rsqrtf((float)c + 1.0f);  // +1 self loop
        }
        if (g == N - 1) off[N] = E;
    }
    __syncthreads();
    if (t < 64) hcnt[t] = hoff[t];  // cursors
    __syncthreads();

    for (int e = start + t; e < endi; e += 256) {
        int v = esA[e];
        int pos = atomicAdd(&hcnt[(v >> 24) & 63], 1);
        esB[pos] = v & 0xFFFFFF;
    }
}

// ---------- GEMM (R4 staged-LDS design, FP16 epilogue) ----------
// Block: 64 rows x 64 cols; wave wv -> cols [16wv,16wv+16); lane = row; acc[16].
// K chunked by 32; chunk staged transposed in LDS [32][66]; double buffer.

template <int K, bool TRANS>  // TRANS: stage lrelu(v + b0[k])
__global__ __launch_bounds__(256) void k_gemm(const float* __restrict__ A,
                                              const float* __restrict__ W,
                                              const float* __restrict__ b0,
                                              const float* __restrict__ dinv,
                                              __half* __restrict__ hout, int N) {
    constexpr int CH = 32, NCH = K / CH, LSTR = 66;
    __shared__ float xs[2 * CH * LSTR];
    int t = threadIdx.x;
    int lane = t & 63;
    int wvu = __builtin_amdgcn_readfirstlane(t >> 6);
    int rowBase = blockIdx.x * 64;
    int row = rowBase + lane;

    float4 st[2];
    auto load_chunk = [&](int c) {
#pragma unroll
        for (int i = 0; i < 2; ++i) {
            int g = i * 256 + t;
            int r = g >> 3, kq = g & 7;
            int gr = rowBase + r; if (gr >= N) gr = N - 1;
            float4 v = *(const float4*)(A + (size_t)gr * K + c * CH + kq * 4);
            if (TRANS) {
                float4 b = *(const float4*)(b0 + c * CH + kq * 4);
                v.x = lrelu(v.x + b.x); v.y = lrelu(v.y + b.y);
                v.z = lrelu(v.z + b.z); v.w = lrelu(v.w + b.w);
            }
            st[i] = v;
        }
    };
    auto write_chunk = [&](int buf) {
        float* bb = xs + buf * (CH * LSTR);
#pragma unroll
        for (int i = 0; i < 2; ++i) {
            int g = i * 256 + t;
            int r = g >> 3, kq = g & 7;
            bb[(kq * 4 + 0) * LSTR + r] = st[i].x;
            bb[(kq * 4 + 1) * LSTR + r] = st[i].y;
            bb[(kq * 4 + 2) * LSTR + r] = st[i].z;
            bb[(kq * 4 + 3) * LSTR + r] = st[i].w;
        }
    };

    float acc[16];
#pragma unroll
    for (int c = 0; c < 16; ++c) acc[c] = 0.0f;

    load_chunk(0);
    write_chunk(0);
    __syncthreads();

    for (int c = 0; c < NCH; ++c) {
        if (c + 1 < NCH) load_chunk(c + 1);
        const float* xb = xs + (c & 1) * (CH * LSTR) + lane;
#pragma unroll
        for (int kk = 0; kk < CH; ++kk) {
            float xv = xb[kk * LSTR];
            const float4* W4 = (const float4*)(W + (size_t)(c * CH + kk) * 64 + wvu * 16);
            float4 w0 = W4[0], w1 = W4[1], w2 = W4[2], w3 = W4[3];  // scalar loads
            acc[0]  = fmaf(xv, w0.x, acc[0]);  acc[1]  = fmaf(xv, w0.y, acc[1]);
            acc[2]  = fmaf(xv, w0.z, acc[2]);  acc[3]  = fmaf(xv, w0.w, acc[3]);
            acc[4]  = fmaf(xv, w1.x, acc[4]);  acc[5]  = fmaf(xv, w1.y, acc[5]);
            acc[6]  = fmaf(xv, w1.z, acc[6]);  acc[7]  = fmaf(xv, w1.w, acc[7]);
            acc[8]  = fmaf(xv, w2.x, acc[8]);  acc[9]  = fmaf(xv, w2.y, acc[9]);
            acc[10] = fmaf(xv, w2.z, acc[10]); acc[11] = fmaf(xv, w2.w, acc[11]);
            acc[12] = fmaf(xv, w3.x, acc[12]); acc[13] = fmaf(xv, w3.y, acc[13]);
            acc[14] = fmaf(xv, w3.z, acc[14]); acc[15] = fmaf(xv, w3.w, acc[15]);
        }
        if (c + 1 < NCH) write_chunk((c + 1) & 1);
        __syncthreads();
    }

    if (row >= N) return;
    float dv = dinv[row];
    __half2 p[8];
#pragma unroll
    for (int q = 0; q < 8; ++q)
        p[q] = __floats2half2_rn(acc[2 * q] * dv, acc[2 * q + 1] * dv);
    __half* o = hout + (size_t)row * 64 + wvu * 16;
    ((uint4*)o)[0] = ((uint4*)p)[0];
    ((uint4*)o)[1] = ((uint4*)p)[1];
}

// ---------- aggregation: one wave per node, FP16 gather, 4 edges in flight ----------

__global__ __launch_bounds__(256) void k_agg(const int* __restrict__ off,
                                             const int* __restrict__ esB,
                                             const float* __restrict__ dinv,
                                             const __half* __restrict__ hs,
                                             float* __restrict__ agg, int N) {
    int lane = threadIdx.x & 63;
    int node = (blockIdx.x * blockDim.x + threadIdx.x) >> 6;
    if (node >= N) return;
    int half = lane >> 5, l = lane & 31;
    int beg = off[node], end = off[node + 1];

    float ax = 0.0f, ay = 0.0f;
    if (half == 0) {  // self loop
        float2 f = __half22float2(*(const __half2*)(hs + (size_t)node * 64 + 2 * l));
        ax = f.x; ay = f.y;
    }
    int j = beg + 1 - half;  // half0: odd rel idx, half1: even rel idx
    for (; j + 2 < end; j += 4) {
        int s0 = esB[j], s1 = esB[j + 2];
        float2 v0 = __half22float2(*(const __half2*)(hs + (size_t)s0 * 64 + 2 * l));
        float2 v1 = __half22float2(*(const __half2*)(hs + (size_t)s1 * 64 + 2 * l));
        ax += v0.x + v1.x; ay += v0.y + v1.y;
    }
    if (j < end) {
        int s0 = esB[j];
        float2 v0 = __half22float2(*(const __half2*)(hs + (size_t)s0 * 64 + 2 * l));
        ax += v0.x; ay += v0.y;
    }
    ax += __shfl(ax, lane ^ 32);
    ay += __shfl(ay, lane ^ 32);
    if (half == 0) {
        float dv = dinv[node];
        float2 o; o.x = ax * dv; o.y = ay * dv;
        *(float2*)(agg + (size_t)node * 64 + 2 * l) = o;
    }
}

// ---------- epilogue ----------

__global__ void k_out(const int* __restrict__ idx, const float* __restrict__ agg,
                      const float* __restrict__ b1, const float* __restrict__ Wm,
                      const float* __restrict__ bm, float* __restrict__ out, int NSEL) {
    int lane = threadIdx.x & 63;
    int wv = (blockIdx.x * blockDim.x + threadIdx.x) >> 6;
    if (wv >= NSEL) return;
    int node = idx[wv];
    float hs = lrelu(agg[(size_t)node * 64 + lane] + b1[lane]);
    out[(size_t)wv * 64 + lane] = hs;
#pragma unroll
    for (int o = 0; o < 5; ++o) {
        float p = hs * Wm[lane * 5 + o];
#pragma unroll
        for (int offs = 32; offs > 0; offs >>= 1) p += __shfl_down(p, offs);
        if (lane == 0)
            out[(size_t)NSEL * 64 + (size_t)wv * 5 + o] =
                1.0f / (1.0f + expf(-(p + bm[o])));
    }
}

extern "C" void kernel_launch(void* const* d_in, const int* in_sizes, int n_in,
                              void* d_out, int out_size, void* d_ws, size_t ws_size,
                              hipStream_t stream) {
    const float* x   = (const float*)d_in[0];
    const int*   ei  = (const int*)d_in[1];
    const int*   idx = (const int*)d_in[2];
    const float* W0  = (const float*)d_in[3];
    const float* b0  = (const float*)d_in[4];
    const float* W1  = (const float*)d_in[5];
    const float* b1  = (const float*)d_in[6];
    const float* Wm  = (const float*)d_in[7];
    const float* bm  = (const float*)d_in[8];

    int N    = in_sizes[0] / 128;
    int E    = in_sizes[1] / 2;
    int NSEL = in_sizes[2];
    const int* src = ei;
    const int* dst = ei + E;

    int B  = (N + 63) / 64;      // dst buckets (64 nodes each)
    int BP = B * NPART;

    char* w = (char*)d_ws;
    size_t Na  = ((size_t)N + 1023) & ~(size_t)1023;
    size_t Ea  = ((size_t)E + 1023) & ~(size_t)1023;
    size_t BPa = ((size_t)BP + 1023) & ~(size_t)1023;
    float*  dinv  = (float*)w;                w += Na * 4;
    int*    phist = (int*)w;                  w += BPa * 4;
    int*    pbase = (int*)w;                  w += (BPa + 1024) * 4;
    int*    bsum  = (int*)w;                  w += 1024 * 4;
    int*    off   = (int*)w;                  w += (Na + 1024) * 4;
    int*    esA   = (int*)w;                  w += Ea * 4;
    int*    esB   = (int*)w;                  w += Ea * 4;
    __half* hs16  = (__half*)w;               w += (size_t)N * 64 * 2;
    float*  agg   = (float*)w;                                          // N*64*4

    int nbp = (BP + 1023) / 1024;

    k_part_hist<<<NPART, 256, 0, stream>>>(dst, E, B, phist);
    k_blocksum<<<nbp, 256, 0, stream>>>(phist, BP, bsum);
    k_scan_bsum<<<1, 1024, 0, stream>>>(bsum, nbp, pbase + BP);
    k_scan_block<<<nbp, 256, 0, stream>>>(phist, bsum, pbase, BP);
    k_part_scatter<<<NPART, 256, 0, stream>>>(src, dst, E, B, pbase, esA);
    k_bsort<<<B, 256, 0, stream>>>(pbase, BP, esA, esB, off, dinv, N, E);

    int gemm_blocks = (N + 63) / 64;
    int agg_blocks  = (N + 3) / 4;

    k_gemm<128, false><<<gemm_blocks, 256, 0, stream>>>(x, W0, nullptr, dinv, hs16, N);
    k_agg<<<agg_blocks, 256, 0, stream>>>(off, esB, dinv, hs16, agg, N);
    k_gemm<64, true><<<gemm_blocks, 256, 0, stream>>>(agg, W1, b0, dinv, hs16, N);
    k_agg<<<agg_blocks, 256, 0, stream>>>(off, esB, dinv, hs16, agg, N);
    k_out<<<(NSEL + 3) / 4, 256, 0, stream>>>(idx, agg, b1, Wm, bm, (float*)d_out, NSEL);
}

// Round 7
// 277.599 us; speedup vs baseline: 5.5280x; 1.6012x over previous
//
#include <hip/hip_runtime.h>
#include <hip/hip_fp16.h>
#include <math.h>

// GCN: h0 = lrelu(Agg(x@W0)+b0); h1 = lrelu(Agg(h0@W1)+b1); out = sigmoid(h1[idx]@Wm+bm)
// Agg (sym-norm + self loops): agg[d] = dinv[d] * ( sum_{e:dst=d} hs[src] + hs[d] ),
// hs = h * dinv[row], stored FP16. Layer-1 agg fuses b0+lrelu so GEMM2 is a pure matmul.
// CSR build: partition-binned scatter (64 blocks x 1024 thr, ILP-4) + per-bucket LDS
// counting sort (emits node-ordered edges, off[], dinv[]).
// GEMM: fp16 MFMA 16x16x32, fp32 accum; block = 64 rows; x & W^T staged fp16 in LDS.

#define NPART 64
#define MAXB 2048  // max dst-buckets (N <= 131072)

typedef _Float16 h8 __attribute__((ext_vector_type(8)));
typedef float f4v __attribute__((ext_vector_type(4)));

__device__ __forceinline__ float lrelu(float x) { return x > 0.0f ? x : 0.01f * x; }

// ---------- partitioned binning (1024 threads, 4-edge ILP) ----------

__global__ __launch_bounds__(1024) void k_part_hist(const int* __restrict__ dst, int E,
                                                    int B, int* __restrict__ phist) {
    __shared__ int scnt[MAXB];
    int t = threadIdx.x, p = blockIdx.x;
    for (int i = t; i < B; i += 1024) scnt[i] = 0;
    __syncthreads();
    int ep = (((E + NPART - 1) / NPART) + 3) & ~3;
    int beg = p * ep, endi = min(E, beg + ep);
    int cnt4 = (endi - beg) >> 2;
    for (int i = t; i < cnt4; i += 1024) {
        int4 d = *(const int4*)(dst + beg + i * 4);
        atomicAdd(&scnt[d.x >> 6], 1);
        atomicAdd(&scnt[d.y >> 6], 1);
        atomicAdd(&scnt[d.z >> 6], 1);
        atomicAdd(&scnt[d.w >> 6], 1);
    }
    int rem = (endi - beg) & 3;
    if (t < rem) atomicAdd(&scnt[dst[beg + cnt4 * 4 + t] >> 6], 1);
    __syncthreads();
    for (int i = t; i < B; i += 1024) phist[i * NPART + p] = scnt[i];
}

__global__ __launch_bounds__(1024) void k_part_scatter(const int* __restrict__ src,
                                                       const int* __restrict__ dst, int E,
                                                       int B, const int* __restrict__ pbase,
                                                       int* __restrict__ esA) {
    __shared__ int sbase[MAXB];
    int t = threadIdx.x, p = blockIdx.x;
    for (int i = t; i < B; i += 1024) sbase[i] = pbase[i * NPART + p];
    __syncthreads();
    int ep = (((E + NPART - 1) / NPART) + 3) & ~3;
    int beg = p * ep, endi = min(E, beg + ep);
    int cnt4 = (endi - beg) >> 2;
    for (int i = t; i < cnt4; i += 1024) {
        int e = beg + i * 4;
        int4 d = *(const int4*)(dst + e);
        int4 s = *(const int4*)(src + e);
        int p0 = atomicAdd(&sbase[d.x >> 6], 1);
        int p1 = atomicAdd(&sbase[d.y >> 6], 1);
        int p2 = atomicAdd(&sbase[d.z >> 6], 1);
        int p3 = atomicAdd(&sbase[d.w >> 6], 1);
        esA[p0] = ((d.x & 63) << 24) | s.x;
        esA[p1] = ((d.y & 63) << 24) | s.y;
        esA[p2] = ((d.z & 63) << 24) | s.z;
        esA[p3] = ((d.w & 63) << 24) | s.w;
    }
    int rem = (endi - beg) & 3;
    if (t < rem) {
        int e = beg + cnt4 * 4 + t;
        int d = dst[e];
        int pos = atomicAdd(&sbase[d >> 6], 1);
        esA[pos] = ((d & 63) << 24) | src[e];
    }
}

// ---------- scan over BP = B*NPART ----------

__global__ void k_blocksum(const int* __restrict__ cnt, int N, int* __restrict__ bsum) {
    __shared__ int sm[256];
    int b = blockIdx.x, t = threadIdx.x;
    int base = b * 1024 + t * 4;
    int s = 0;
#pragma unroll
    for (int i = 0; i < 4; ++i) { int j = base + i; if (j < N) s += cnt[j]; }
    sm[t] = s; __syncthreads();
    for (int off = 128; off > 0; off >>= 1) {
        if (t < off) sm[t] += sm[t + off];
        __syncthreads();
    }
    if (t == 0) bsum[b] = sm[0];
}

__global__ void k_scan_bsum(int* __restrict__ bsum, int nb, int* __restrict__ offN) {
    __shared__ int sm[1024];
    int t = threadIdx.x;
    int v = (t < nb) ? bsum[t] : 0;
    sm[t] = v; __syncthreads();
    for (int d = 1; d < 1024; d <<= 1) {
        int add = (t >= d) ? sm[t - d] : 0;
        __syncthreads();
        sm[t] += add;
        __syncthreads();
    }
    if (t < nb) bsum[t] = sm[t] - v;       // exclusive
    if (t == nb - 1) *offN = sm[t];        // total == E
}

__global__ void k_scan_block(const int* __restrict__ cnt, const int* __restrict__ bsum,
                             int* __restrict__ off, int N) {
    __shared__ int sm[256];
    int b = blockIdx.x, t = threadIdx.x;
    int base = b * 1024 + t * 4;
    int v[4];
#pragma unroll
    for (int i = 0; i < 4; ++i) { int j = base + i; v[i] = (j < N) ? cnt[j] : 0; }
    int tsum = v[0] + v[1] + v[2] + v[3];
    sm[t] = tsum; __syncthreads();
    for (int d = 1; d < 256; d <<= 1) {
        int val = (t >= d) ? sm[t - d] : 0;
        __syncthreads();
        sm[t] += val;
        __syncthreads();
    }
    int run = sm[t] - tsum + bsum[b];
#pragma unroll
    for (int i = 0; i < 4; ++i) {
        int j = base + i;
        if (j < N) off[j] = run;
        run += v[i];
    }
}

// ---------- per-bucket counting sort -> node-ordered edges + off[] + dinv[] ----------

__global__ __launch_bounds__(256) void k_bsort(const int* __restrict__ pbase, int BP,
                                               const int* __restrict__ esA,
                                               int* __restrict__ esB,
                                               int* __restrict__ off,
                                               float* __restrict__ dinv,
                                               int N, int E) {
    __shared__ int hcnt[64];
    __shared__ int hoff[64];
    int t = threadIdx.x, b = blockIdx.x;
    int start = pbase[b * NPART];
    int endi  = pbase[min((b + 1) * NPART, BP)];
    int cnt = endi - start;

    if (t < 64) hcnt[t] = 0;
    __syncthreads();
    for (int i = t * 4; i < cnt; i += 1024) {
#pragma unroll
        for (int c = 0; c < 4; ++c)
            if (i + c < cnt) atomicAdd(&hcnt[(esA[start + i + c] >> 24) & 63], 1);
    }
    __syncthreads();

    if (t < 64) {  // wave 0: 64-wide scan -> exclusive offsets
        int c = hcnt[t];
        int v = c;
#pragma unroll
        for (int d = 1; d < 64; d <<= 1) {
            int u = __shfl_up(v, d);
            if (t >= d) v += u;
        }
        int pos = start + (v - c);
        hoff[t] = pos;
        int g = b * 64 + t;
        if (g < N) {
            off[g] = pos;
            dinv[g] = rsqrtf((float)c + 1.0f);  // +1 self loop
        }
        if (g == N - 1) off[N] = E;
    }
    __syncthreads();
    if (t < 64) hcnt[t] = hoff[t];  // cursors
    __syncthreads();

    for (int i = t * 4; i < cnt; i += 1024) {
#pragma unroll
        for (int c = 0; c < 4; ++c)
            if (i + c < cnt) {
                int v = esA[start + i + c];
                int pos = atomicAdd(&hcnt[(v >> 24) & 63], 1);
                esB[pos] = v & 0xFFFFFF;
            }
    }
}

// ---------- GEMM: fp16 MFMA 16x16x32, fp32 accumulate ----------
// Block 256 = 4 waves; 64 rows/block; wave wv -> rows [16wv,16wv+16), all 64 cols.
// a16[64][K+8] fp16 (x rows), wt16[64][K+8] fp16 (W^T rows). Pad 8 halves: b128
// reads land 2 lanes/bank (free).

template <int K>
__global__ __launch_bounds__(256) void k_gemm(const float* __restrict__ A,
                                              const float* __restrict__ W,
                                              const float* __restrict__ dinv,
                                              __half* __restrict__ hout, int N) {
    constexpr int ASTR = K + 8;
    __shared__ _Float16 a16[64 * ASTR];
    __shared__ _Float16 wt16[64 * ASTR];
    int t = threadIdx.x, lane = t & 63, wv = t >> 6;
    int rowBase = blockIdx.x * 64;

    // stage A rows -> fp16
#pragma unroll
    for (int i = 0; i < K / 16; ++i) {              // (64*K/4)/256 float4 per thread
        int g = i * 256 + t;
        int r = g / (K / 4), kq = g % (K / 4);
        int gr = rowBase + r; if (gr >= N) gr = N - 1;
        float4 v = *(const float4*)(A + (size_t)gr * K + kq * 4);
        _Float16* p = a16 + r * ASTR + kq * 4;
        *(__half2*)(p)     = __floats2half2_rn(v.x, v.y);
        *(__half2*)(p + 2) = __floats2half2_rn(v.z, v.w);
    }
    // stage W^T -> fp16
#pragma unroll
    for (int i = 0; i < K / 16; ++i) {              // (K*64/4)/256 float4 per thread
        int g = i * 256 + t;
        int k = g >> 4, nq = g & 15;
        float4 v = *(const float4*)(W + (size_t)k * 64 + nq * 4);
        wt16[(nq * 4 + 0) * ASTR + k] = (_Float16)v.x;
        wt16[(nq * 4 + 1) * ASTR + k] = (_Float16)v.y;
        wt16[(nq * 4 + 2) * ASTR + k] = (_Float16)v.z;
        wt16[(nq * 4 + 3) * ASTR + k] = (_Float16)v.w;
    }
    __syncthreads();

    int m = lane & 15, q = lane >> 4;
    f4v acc[4] = {{0,0,0,0},{0,0,0,0},{0,0,0,0},{0,0,0,0}};
    const _Float16* arow = a16 + (wv * 16 + m) * ASTR + q * 8;
#pragma unroll
    for (int kt = 0; kt < K / 32; ++kt) {
        h8 af = *(const h8*)(arow + kt * 32);
#pragma unroll
        for (int nt = 0; nt < 4; ++nt) {
            h8 bf = *(const h8*)(wt16 + (nt * 16 + m) * ASTR + kt * 32 + q * 8);
            acc[nt] = __builtin_amdgcn_mfma_f32_16x16x32_f16(af, bf, acc[nt], 0, 0, 0);
        }
    }

    // epilogue: lane holds D[row=q*4+reg][col=nt*16+m] of this wave's 16-row tile
    int r0 = rowBase + wv * 16 + q * 4;
#pragma unroll
    for (int reg = 0; reg < 4; ++reg) {
        int row = r0 + reg;
        if (row >= N) continue;
        float dv = dinv[row];
#pragma unroll
        for (int nt = 0; nt < 4; ++nt)
            hout[(size_t)row * 64 + nt * 16 + m] = (__half)(acc[nt][reg] * dv);
    }
}

// ---------- aggregation: wave per node; quarter-waves = 4 edge streams ----------
// lane = (qt, l16): gather uint2 (4 halves) at hs[src*64 + l16*4]; one instr = 128B row.
// APPLY: layer-1 fuses a = lrelu(sum*dinv + b0).

template <bool APPLY>
__global__ __launch_bounds__(256) void k_agg(const int* __restrict__ off,
                                             const int* __restrict__ esB,
                                             const float* __restrict__ dinv,
                                             const __half* __restrict__ hs,
                                             const float* __restrict__ b0,
                                             float* __restrict__ agg, int N) {
    int lane = threadIdx.x & 63;
    int node = (blockIdx.x * blockDim.x + threadIdx.x) >> 6;
    if (node >= N) return;
    int qt = lane >> 4, l16 = lane & 15;
    int beg = off[node], end = off[node + 1];

    float ax = 0, ay = 0, az = 0, aw = 0;
    auto addrow = [&](int s) {
        uint2 u = *(const uint2*)(hs + (size_t)s * 64 + l16 * 4);
        float2 f0 = __half22float2(*(__half2*)&u.x);
        float2 f1 = __half22float2(*(__half2*)&u.y);
        ax += f0.x; ay += f0.y; az += f1.x; aw += f1.y;
    };
    if (qt == 0) addrow(node);  // self loop
    int j = beg + qt;
    for (; j + 4 < end; j += 8) { addrow(esB[j]); addrow(esB[j + 4]); }
    if (j < end) addrow(esB[j]);

#pragma unroll
    for (int d = 16; d <= 32; d <<= 1) {
        ax += __shfl_xor(ax, d); ay += __shfl_xor(ay, d);
        az += __shfl_xor(az, d); aw += __shfl_xor(aw, d);
    }
    if (qt == 0) {
        float dv = dinv[node];
        float4 o; o.x = ax * dv; o.y = ay * dv; o.z = az * dv; o.w = aw * dv;
        if (APPLY) {
            float4 b = *(const float4*)(b0 + l16 * 4);
            o.x = lrelu(o.x + b.x); o.y = lrelu(o.y + b.y);
            o.z = lrelu(o.z + b.z); o.w = lrelu(o.w + b.w);
        }
        *(float4*)(agg + (size_t)node * 64 + l16 * 4) = o;
    }
}

// ---------- epilogue ----------

__global__ void k_out(const int* __restrict__ idx, const float* __restrict__ agg,
                      const float* __restrict__ b1, const float* __restrict__ Wm,
                      const float* __restrict__ bm, float* __restrict__ out, int NSEL) {
    int lane = threadIdx.x & 63;
    int wv = (blockIdx.x * blockDim.x + threadIdx.x) >> 6;
    if (wv >= NSEL) return;
    int node = idx[wv];
    float hs = lrelu(agg[(size_t)node * 64 + lane] + b1[lane]);
    out[(size_t)wv * 64 + lane] = hs;
#pragma unroll
    for (int o = 0; o < 5; ++o) {
        float p = hs * Wm[lane * 5 + o];
#pragma unroll
        for (int offs = 32; offs > 0; offs >>= 1) p += __shfl_down(p, offs);
        if (lane == 0)
            out[(size_t)NSEL * 64 + (size_t)wv * 5 + o] =
                1.0f / (1.0f + expf(-(p + bm[o])));
    }
}

extern "C" void kernel_launch(void* const* d_in, const int* in_sizes, int n_in,
                              void* d_out, int out_size, void* d_ws, size_t ws_size,
                              hipStream_t stream) {
    const float* x   = (const float*)d_in[0];
    const int*   ei  = (const int*)d_in[1];
    const int*   idx = (const int*)d_in[2];
    const float* W0  = (const float*)d_in[3];
    const float* b0  = (const float*)d_in[4];
    const float* W1  = (const float*)d_in[5];
    const float* b1  = (const float*)d_in[6];
    const float* Wm  = (const float*)d_in[7];
    const float* bm  = (const float*)d_in[8];

    int N    = in_sizes[0] / 128;
    int E    = in_sizes[1] / 2;
    int NSEL = in_sizes[2];
    const int* src = ei;
    const int* dst = ei + E;

    int B  = (N + 63) / 64;
    int BP = B * NPART;

    char* w = (char*)d_ws;
    size_t Na  = ((size_t)N + 1023) & ~(size_t)1023;
    size_t Ea  = ((size_t)E + 1023) & ~(size_t)1023;
    size_t BPa = ((size_t)BP + 1023) & ~(size_t)1023;
    float*  dinv  = (float*)w;                w += Na * 4;
    int*    phist = (int*)w;                  w += BPa * 4;
    int*    pbase = (int*)w;                  w += (BPa + 1024) * 4;
    int*    bsum  = (int*)w;                  w += 1024 * 4;
    int*    off   = (int*)w;                  w += (Na + 1024) * 4;
    int*    esA   = (int*)w;                  w += Ea * 4;
    int*    esB   = (int*)w;                  w += Ea * 4;
    __half* hs16  = (__half*)w;               w += (size_t)N * 64 * 2;
    float*  agg   = (float*)w;                                          // N*64*4

    int nbp = (BP + 1023) / 1024;

    k_part_hist<<<NPART, 1024, 0, stream>>>(dst, E, B, phist);
    k_blocksum<<<nbp, 256, 0, stream>>>(phist, BP, bsum);
    k_scan_bsum<<<1, 1024, 0, stream>>>(bsum, nbp, pbase + BP);
    k_scan_block<<<nbp, 256, 0, stream>>>(phist, bsum, pbase, BP);
    k_part_scatter<<<NPART, 1024, 0, stream>>>(src, dst, E, B, pbase, esA);
    k_bsort<<<B, 256, 0, stream>>>(pbase, BP, esA, esB, off, dinv, N, E);

    int gemm_blocks = (N + 63) / 64;
    int agg_blocks  = (N + 3) / 4;

    k_gemm<128><<<gemm_blocks, 256, 0, stream>>>(x, W0, dinv, hs16, N);
    k_agg<true><<<agg_blocks, 256, 0, stream>>>(off, esB, dinv, hs16, b0, agg, N);
    k_gemm<64><<<gemm_blocks, 256, 0, stream>>>(agg, W1, dinv, hs16, N);
    k_agg<false><<<agg_blocks, 256, 0, stream>>>(off, esB, dinv, hs16, nullptr, agg, N);
    k_out<<<(NSEL + 3) / 4, 256, 0, stream>>>(idx, agg, b1, Wm, bm, (float*)d_out, NSEL);
}

// Round 8
// 259.167 us; speedup vs baseline: 5.9211x; 1.0711x over previous
//
#include <hip/hip_runtime.h>
#include <hip/hip_fp16.h>
#include <math.h>

// GCN: h0 = lrelu(Agg(x@W0)+b0); h1 = lrelu(Agg(h0@W1)+b1); out = sigmoid(h1[idx]@Wm+bm)
// Agg (sym-norm + self loops): agg[d] = dinv[d] * ( sum_{e:dst=d} hs[src] + hs[d] ),
// hs = h * dinv[row], stored FP16.
// Key structure: layer-2 aggregation is computed ONLY for the 20k selected nodes,
// fused with b1+lrelu+head matvec+sigmoid in k_aggout (edges into selected nodes
// are ~20% of E). Layer-1 agg fuses b0+lrelu and writes fp16 (GEMM2 A operand).
// CSR build: partition-binned scatter + per-bucket LDS counting sort.
// GEMM: fp16 MFMA 16x16x32, fp32 accum.

#define NPART 64
#define MAXB 2048  // max dst-buckets (N <= 131072)

typedef _Float16 h8 __attribute__((ext_vector_type(8)));
typedef float f4v __attribute__((ext_vector_type(4)));

__device__ __forceinline__ float lrelu(float x) { return x > 0.0f ? x : 0.01f * x; }

// ---------- partitioned binning (1024 threads, 4-edge ILP) ----------

__global__ __launch_bounds__(1024) void k_part_hist(const int* __restrict__ dst, int E,
                                                    int B, int* __restrict__ phist) {
    __shared__ int scnt[MAXB];
    int t = threadIdx.x, p = blockIdx.x;
    for (int i = t; i < B; i += 1024) scnt[i] = 0;
    __syncthreads();
    int ep = (((E + NPART - 1) / NPART) + 3) & ~3;
    int beg = p * ep, endi = min(E, beg + ep);
    int cnt4 = (endi - beg) >> 2;
    for (int i = t; i < cnt4; i += 1024) {
        int4 d = *(const int4*)(dst + beg + i * 4);
        atomicAdd(&scnt[d.x >> 6], 1);
        atomicAdd(&scnt[d.y >> 6], 1);
        atomicAdd(&scnt[d.z >> 6], 1);
        atomicAdd(&scnt[d.w >> 6], 1);
    }
    int rem = (endi - beg) & 3;
    if (t < rem) atomicAdd(&scnt[dst[beg + cnt4 * 4 + t] >> 6], 1);
    __syncthreads();
    for (int i = t; i < B; i += 1024) phist[i * NPART + p] = scnt[i];
}

__global__ __launch_bounds__(1024) void k_part_scatter(const int* __restrict__ src,
                                                       const int* __restrict__ dst, int E,
                                                       int B, const int* __restrict__ pbase,
                                                       int* __restrict__ esA) {
    __shared__ int sbase[MAXB];
    int t = threadIdx.x, p = blockIdx.x;
    for (int i = t; i < B; i += 1024) sbase[i] = pbase[i * NPART + p];
    __syncthreads();
    int ep = (((E + NPART - 1) / NPART) + 3) & ~3;
    int beg = p * ep, endi = min(E, beg + ep);
    int cnt4 = (endi - beg) >> 2;
    for (int i = t; i < cnt4; i += 1024) {
        int e = beg + i * 4;
        int4 d = *(const int4*)(dst + e);
        int4 s = *(const int4*)(src + e);
        int p0 = atomicAdd(&sbase[d.x >> 6], 1);
        int p1 = atomicAdd(&sbase[d.y >> 6], 1);
        int p2 = atomicAdd(&sbase[d.z >> 6], 1);
        int p3 = atomicAdd(&sbase[d.w >> 6], 1);
        esA[p0] = ((d.x & 63) << 24) | s.x;
        esA[p1] = ((d.y & 63) << 24) | s.y;
        esA[p2] = ((d.z & 63) << 24) | s.z;
        esA[p3] = ((d.w & 63) << 24) | s.w;
    }
    int rem = (endi - beg) & 3;
    if (t < rem) {
        int e = beg + cnt4 * 4 + t;
        int d = dst[e];
        int pos = atomicAdd(&sbase[d >> 6], 1);
        esA[pos] = ((d & 63) << 24) | src[e];
    }
}

// ---------- scan over BP = B*NPART ----------

__global__ void k_blocksum(const int* __restrict__ cnt, int N, int* __restrict__ bsum) {
    __shared__ int sm[256];
    int b = blockIdx.x, t = threadIdx.x;
    int base = b * 1024 + t * 4;
    int s = 0;
#pragma unroll
    for (int i = 0; i < 4; ++i) { int j = base + i; if (j < N) s += cnt[j]; }
    sm[t] = s; __syncthreads();
    for (int off = 128; off > 0; off >>= 1) {
        if (t < off) sm[t] += sm[t + off];
        __syncthreads();
    }
    if (t == 0) bsum[b] = sm[0];
}

__global__ void k_scan_bsum(int* __restrict__ bsum, int nb, int* __restrict__ offN) {
    __shared__ int sm[1024];
    int t = threadIdx.x;
    int v = (t < nb) ? bsum[t] : 0;
    sm[t] = v; __syncthreads();
    for (int d = 1; d < 1024; d <<= 1) {
        int add = (t >= d) ? sm[t - d] : 0;
        __syncthreads();
        sm[t] += add;
        __syncthreads();
    }
    if (t < nb) bsum[t] = sm[t] - v;       // exclusive
    if (t == nb - 1) *offN = sm[t];        // total == E
}

__global__ void k_scan_block(const int* __restrict__ cnt, const int* __restrict__ bsum,
                             int* __restrict__ off, int N) {
    __shared__ int sm[256];
    int b = blockIdx.x, t = threadIdx.x;
    int base = b * 1024 + t * 4;
    int v[4];
#pragma unroll
    for (int i = 0; i < 4; ++i) { int j = base + i; v[i] = (j < N) ? cnt[j] : 0; }
    int tsum = v[0] + v[1] + v[2] + v[3];
    sm[t] = tsum; __syncthreads();
    for (int d = 1; d < 256; d <<= 1) {
        int val = (t >= d) ? sm[t - d] : 0;
        __syncthreads();
        sm[t] += val;
        __syncthreads();
    }
    int run = sm[t] - tsum + bsum[b];
#pragma unroll
    for (int i = 0; i < 4; ++i) {
        int j = base + i;
        if (j < N) off[j] = run;
        run += v[i];
    }
}

// ---------- per-bucket counting sort -> node-ordered edges + off[] + dinv[] ----------

__global__ __launch_bounds__(256) void k_bsort(const int* __restrict__ pbase, int BP,
                                               const int* __restrict__ esA,
                                               int* __restrict__ esB,
                                               int* __restrict__ off,
                                               float* __restrict__ dinv,
                                               int N, int E) {
    __shared__ int hcnt[64];
    __shared__ int hoff[64];
    int t = threadIdx.x, b = blockIdx.x;
    int start = pbase[b * NPART];
    int endi  = pbase[min((b + 1) * NPART, BP)];
    int cnt = endi - start;

    if (t < 64) hcnt[t] = 0;
    __syncthreads();
    for (int i = t * 4; i < cnt; i += 1024) {
#pragma unroll
        for (int c = 0; c < 4; ++c)
            if (i + c < cnt) atomicAdd(&hcnt[(esA[start + i + c] >> 24) & 63], 1);
    }
    __syncthreads();

    if (t < 64) {  // wave 0: 64-wide scan -> exclusive offsets
        int c = hcnt[t];
        int v = c;
#pragma unroll
        for (int d = 1; d < 64; d <<= 1) {
            int u = __shfl_up(v, d);
            if (t >= d) v += u;
        }
        int pos = start + (v - c);
        hoff[t] = pos;
        int g = b * 64 + t;
        if (g < N) {
            off[g] = pos;
            dinv[g] = rsqrtf((float)c + 1.0f);  // +1 self loop
        }
        if (g == N - 1) off[N] = E;
    }
    __syncthreads();
    if (t < 64) hcnt[t] = hoff[t];  // cursors
    __syncthreads();

    for (int i = t * 4; i < cnt; i += 1024) {
#pragma unroll
        for (int c = 0; c < 4; ++c)
            if (i + c < cnt) {
                int v = esA[start + i + c];
                int pos = atomicAdd(&hcnt[(v >> 24) & 63], 1);
                esB[pos] = v & 0xFFFFFF;
            }
    }
}

// ---------- GEMM: fp16 MFMA 16x16x32, fp32 accumulate ----------
// Block 256 = 4 waves; 64 rows/block; wave wv -> rows [16wv,16wv+16), all 64 cols.
// AT = float (layer1 x) or __half (layer2, agg1 output already fp16).

template <int K, typename AT>
__global__ __launch_bounds__(256) void k_gemm(const AT* __restrict__ A,
                                              const float* __restrict__ W,
                                              const float* __restrict__ dinv,
                                              __half* __restrict__ hout, int N) {
    constexpr int ASTR = K + 8;
    __shared__ _Float16 a16[64 * ASTR];
    __shared__ _Float16 wt16[64 * ASTR];
    int t = threadIdx.x, lane = t & 63, wv = t >> 6;
    int rowBase = blockIdx.x * 64;

    // stage A rows -> fp16 (4 elems per thread-iter)
#pragma unroll
    for (int i = 0; i < K / 16; ++i) {
        int g = i * 256 + t;
        int r = g / (K / 4), kq = g % (K / 4);
        int gr = rowBase + r; if (gr >= N) gr = N - 1;
        _Float16* p = a16 + r * ASTR + kq * 4;
        if constexpr (sizeof(AT) == 4) {
            float4 v = *(const float4*)((const float*)A + (size_t)gr * K + kq * 4);
            *(__half2*)(p)     = __floats2half2_rn(v.x, v.y);
            *(__half2*)(p + 2) = __floats2half2_rn(v.z, v.w);
        } else {
            *(uint2*)p = *(const uint2*)((const __half*)A + (size_t)gr * K + kq * 4);
        }
    }
    // stage W^T -> fp16
#pragma unroll
    for (int i = 0; i < K / 16; ++i) {
        int g = i * 256 + t;
        int k = g >> 4, nq = g & 15;
        float4 v = *(const float4*)(W + (size_t)k * 64 + nq * 4);
        wt16[(nq * 4 + 0) * ASTR + k] = (_Float16)v.x;
        wt16[(nq * 4 + 1) * ASTR + k] = (_Float16)v.y;
        wt16[(nq * 4 + 2) * ASTR + k] = (_Float16)v.z;
        wt16[(nq * 4 + 3) * ASTR + k] = (_Float16)v.w;
    }
    __syncthreads();

    int m = lane & 15, q = lane >> 4;
    f4v acc[4] = {{0,0,0,0},{0,0,0,0},{0,0,0,0},{0,0,0,0}};
    const _Float16* arow = a16 + (wv * 16 + m) * ASTR + q * 8;
#pragma unroll
    for (int kt = 0; kt < K / 32; ++kt) {
        h8 af = *(const h8*)(arow + kt * 32);
#pragma unroll
        for (int nt = 0; nt < 4; ++nt) {
            h8 bf = *(const h8*)(wt16 + (nt * 16 + m) * ASTR + kt * 32 + q * 8);
            acc[nt] = __builtin_amdgcn_mfma_f32_16x16x32_f16(af, bf, acc[nt], 0, 0, 0);
        }
    }

    // epilogue: lane holds D[row=q*4+reg][col=nt*16+m]
    int r0 = rowBase + wv * 16 + q * 4;
#pragma unroll
    for (int reg = 0; reg < 4; ++reg) {
        int row = r0 + reg;
        if (row >= N) continue;
        float dv = dinv[row];
#pragma unroll
        for (int nt = 0; nt < 4; ++nt)
            hout[(size_t)row * 64 + nt * 16 + m] = (__half)(acc[nt][reg] * dv);
    }
}

// ---------- layer-1 aggregation: wave per node, fuses b0+lrelu, writes fp16 ----------
// lane = (qt, l16): 4 edge streams; gather uint2 (4 halves) = 128B row per instr.

__global__ __launch_bounds__(256) void k_agg1(const int* __restrict__ off,
                                              const int* __restrict__ esB,
                                              const float* __restrict__ dinv,
                                              const __half* __restrict__ hs,
                                              const float* __restrict__ b0,
                                              __half* __restrict__ aout, int N) {
    int lane = threadIdx.x & 63;
    int node = (blockIdx.x * blockDim.x + threadIdx.x) >> 6;
    if (node >= N) return;
    int qt = lane >> 4, l16 = lane & 15;
    int beg = off[node], end = off[node + 1];

    float ax = 0, ay = 0, az = 0, aw = 0;
    auto ld = [&](int s) { return *(const uint2*)(hs + (size_t)s * 64 + l16 * 4); };
    auto acc4 = [&](uint2 u) {
        float2 f0 = __half22float2(*(__half2*)&u.x);
        float2 f1 = __half22float2(*(__half2*)&u.y);
        ax += f0.x; ay += f0.y; az += f1.x; aw += f1.y;
    };
    if (qt == 0) acc4(ld(node));  // self loop
    int j = beg + qt;
    for (; j + 12 < end; j += 16) {
        int s0 = esB[j], s1 = esB[j + 4], s2 = esB[j + 8], s3 = esB[j + 12];
        uint2 u0 = ld(s0), u1 = ld(s1), u2 = ld(s2), u3 = ld(s3);
        acc4(u0); acc4(u1); acc4(u2); acc4(u3);
    }
    for (; j < end; j += 4) acc4(ld(esB[j]));

#pragma unroll
    for (int d = 16; d <= 32; d <<= 1) {
        ax += __shfl_xor(ax, d); ay += __shfl_xor(ay, d);
        az += __shfl_xor(az, d); aw += __shfl_xor(aw, d);
    }
    if (qt == 0) {
        float dv = dinv[node];
        float4 b = *(const float4*)(b0 + l16 * 4);
        float ox = lrelu(ax * dv + b.x), oy = lrelu(ay * dv + b.y);
        float oz = lrelu(az * dv + b.z), ow = lrelu(aw * dv + b.w);
        uint2 u;
        *(__half2*)&u.x = __floats2half2_rn(ox, oy);
        *(__half2*)&u.y = __floats2half2_rn(oz, ow);
        *(uint2*)(aout + (size_t)node * 64 + l16 * 4) = u;
    }
}

// ---------- fused selected-node layer-2 agg + b1 + lrelu + head + sigmoid ----------
// wave per output slot: node=idx[wv]; gather its edges only (~20% of E total).

__global__ __launch_bounds__(256) void k_aggout(const int* __restrict__ idx,
                                                const int* __restrict__ off,
                                                const int* __restrict__ esB,
                                                const float* __restrict__ dinv,
                                                const __half* __restrict__ hs,
                                                const float* __restrict__ b1,
                                                const float* __restrict__ Wm,
                                                const float* __restrict__ bm,
                                                float* __restrict__ out, int NSEL) {
    int lane = threadIdx.x & 63;
    int wv = (blockIdx.x * blockDim.x + threadIdx.x) >> 6;
    if (wv >= NSEL) return;
    int node = idx[wv];
    int qt = lane >> 4, l16 = lane & 15;
    int beg = off[node], end = off[node + 1];

    float ax = 0, ay = 0, az = 0, aw = 0;
    auto ld = [&](int s) { return *(const uint2*)(hs + (size_t)s * 64 + l16 * 4); };
    auto acc4 = [&](uint2 u) {
        float2 f0 = __half22float2(*(__half2*)&u.x);
        float2 f1 = __half22float2(*(__half2*)&u.y);
        ax += f0.x; ay += f0.y; az += f1.x; aw += f1.y;
    };
    if (qt == 0) acc4(ld(node));  // self loop
    int j = beg + qt;
    for (; j + 12 < end; j += 16) {
        int s0 = esB[j], s1 = esB[j + 4], s2 = esB[j + 8], s3 = esB[j + 12];
        uint2 u0 = ld(s0), u1 = ld(s1), u2 = ld(s2), u3 = ld(s3);
        acc4(u0); acc4(u1); acc4(u2); acc4(u3);
    }
    for (; j < end; j += 4) acc4(ld(esB[j]));

#pragma unroll
    for (int d = 16; d <= 32; d <<= 1) {  // all lanes end with full sums
        ax += __shfl_xor(ax, d); ay += __shfl_xor(ay, d);
        az += __shfl_xor(az, d); aw += __shfl_xor(aw, d);
    }

    float dv = dinv[node];
    float4 b = *(const float4*)(b1 + l16 * 4);
    float4 hsel;
    hsel.x = lrelu(ax * dv + b.x); hsel.y = lrelu(ay * dv + b.y);
    hsel.z = lrelu(az * dv + b.z); hsel.w = lrelu(aw * dv + b.w);
    if (qt == 0) *(float4*)(out + (size_t)wv * 64 + l16 * 4) = hsel;

    // head: p[o] = sum_c hsel_c * Wm[c][o]; channels 4*l16..4*l16+3 on each lane
    const float* wr = Wm + (size_t)(4 * l16) * 5;
#pragma unroll
    for (int o = 0; o < 5; ++o) {
        float p = hsel.x * wr[o] + hsel.y * wr[5 + o] +
                  hsel.z * wr[10 + o] + hsel.w * wr[15 + o];
        p += __shfl_xor(p, 1); p += __shfl_xor(p, 2);
        p += __shfl_xor(p, 4); p += __shfl_xor(p, 8);
        if (lane == 0)
            out[(size_t)NSEL * 64 + (size_t)wv * 5 + o] =
                1.0f / (1.0f + expf(-(p + bm[o])));
    }
}

extern "C" void kernel_launch(void* const* d_in, const int* in_sizes, int n_in,
                              void* d_out, int out_size, void* d_ws, size_t ws_size,
                              hipStream_t stream) {
    const float* x   = (const float*)d_in[0];
    const int*   ei  = (const int*)d_in[1];
    const int*   idx = (const int*)d_in[2];
    const float* W0  = (const float*)d_in[3];
    const float* b0  = (const float*)d_in[4];
    const float* W1  = (const float*)d_in[5];
    const float* b1  = (const float*)d_in[6];
    const float* Wm  = (const float*)d_in[7];
    const float* bm  = (const float*)d_in[8];

    int N    = in_sizes[0] / 128;
    int E    = in_sizes[1] / 2;
    int NSEL = in_sizes[2];
    const int* src = ei;
    const int* dst = ei + E;

    int B  = (N + 63) / 64;
    int BP = B * NPART;

    char* w = (char*)d_ws;
    size_t Na  = ((size_t)N + 1023) & ~(size_t)1023;
    size_t Ea  = ((size_t)E + 1023) & ~(size_t)1023;
    size_t BPa = ((size_t)BP + 1023) & ~(size_t)1023;
    float*  dinv  = (float*)w;                w += Na * 4;
    int*    phist = (int*)w;                  w += BPa * 4;
    int*    pbase = (int*)w;                  w += (BPa + 1024) * 4;
    int*    bsum  = (int*)w;                  w += 1024 * 4;
    int*    off   = (int*)w;                  w += (Na + 1024) * 4;
    int*    esA   = (int*)w;                  w += Ea * 4;
    int*    esB   = (int*)w;                  w += Ea * 4;
    __half* hs16  = (__half*)w;               w += (size_t)N * 64 * 2;  // h*dinv (layer in/out)
    __half* a16g  = (__half*)w;                                        // lrelu(agg1+b0), fp16

    int nbp = (BP + 1023) / 1024;

    k_part_hist<<<NPART, 1024, 0, stream>>>(dst, E, B, phist);
    k_blocksum<<<nbp, 256, 0, stream>>>(phist, BP, bsum);
    k_scan_bsum<<<1, 1024, 0, stream>>>(bsum, nbp, pbase + BP);
    k_scan_block<<<nbp, 256, 0, stream>>>(phist, bsum, pbase, BP);
    k_part_scatter<<<NPART, 1024, 0, stream>>>(src, dst, E, B, pbase, esA);
    k_bsort<<<B, 256, 0, stream>>>(pbase, BP, esA, esB, off, dinv, N, E);

    int gemm_blocks = (N + 63) / 64;
    int agg_blocks  = (N + 3) / 4;

    k_gemm<128, float><<<gemm_blocks, 256, 0, stream>>>(x, W0, dinv, hs16, N);
    k_agg1<<<agg_blocks, 256, 0, stream>>>(off, esB, dinv, hs16, b0, a16g, N);
    k_gemm<64, __half><<<gemm_blocks, 256, 0, stream>>>(a16g, W1, dinv, hs16, N);
    k_aggout<<<(NSEL + 3) / 4, 256, 0, stream>>>(idx, off, esB, dinv, hs16, b1, Wm, bm,
                                                 (float*)d_out, NSEL);
}